// Round 1
// baseline (134.990 us; speedup 1.0000x reference)
//
#include <hip/hip_runtime.h>

// HiCE: hierarchical cross-entropy over a balanced binary tree of C=1024 leaves.
// Key identity: num[e]/den[e] = S_e / S_{e+1} where S_e is the exp-sum of the
// 2^e-leaf ancestor block of the target. Softmax denominator cancels.

#define NB 2048   // batch
#define NC 1024   // classes (leaves), 2^ND
#define ND 10     // tree depth (edges)

__global__ __launch_bounds__(256) void hice_kernel(
    const float* __restrict__ inputs,   // [NB, NC]
    const int*   __restrict__ target,   // [NB]
    const float* __restrict__ weights,  // [NC, ND]
    float*       __restrict__ out)      // [1]
{
    __shared__ float ex[NC];        // exp(x - max)
    __shared__ float tree[NC - 1];  // levels 1..ND: level e has NC>>e nodes at offset NC - 2^(11-e)
    __shared__ float wmax[4];

    const int b   = blockIdx.x;
    const int tid = threadIdx.x;
    const float* x = inputs + (size_t)b * NC;

    // ---- load 4 elems/thread, block max ----
    float v[4];
    float m = -3.402823466e38f;
#pragma unroll
    for (int i = 0; i < 4; ++i) {
        v[i] = x[tid + 256 * i];
        m = fmaxf(m, v[i]);
    }
#pragma unroll
    for (int off = 32; off > 0; off >>= 1)
        m = fmaxf(m, __shfl_xor(m, off, 64));
    if ((tid & 63) == 0) wmax[tid >> 6] = m;
    __syncthreads();
    m = fmaxf(fmaxf(wmax[0], wmax[1]), fmaxf(wmax[2], wmax[3]));

    // ---- exp into LDS ----
#pragma unroll
    for (int i = 0; i < 4; ++i)
        ex[tid + 256 * i] = expf(v[i] - m);
    __syncthreads();

    // ---- binary sum tree: all ancestor-block sums in one pass ----
    // level 1: 512 nodes at tree[0..512)
    for (int i = tid; i < 512; i += 256)
        tree[i] = ex[2 * i] + ex[2 * i + 1];
    __syncthreads();
#pragma unroll
    for (int e = 2; e <= ND; ++e) {
        const int n = NC >> e;
        const float* src = tree + (NC - (1 << (12 - e)));  // level e-1
        float*       dst = tree + (NC - (1 << (11 - e)));  // level e
        if (tid < n) dst[tid] = src[2 * tid] + src[2 * tid + 1];
        __syncthreads();
    }

    // ---- per-sample loss on thread 0 ----
    if (tid == 0) {
        const int t = target[b];
        const float* wrow = weights + (size_t)t * ND;
        float S_prev = ex[t];   // S_0 = exp mass of the leaf itself
        float loss = 0.0f;
#pragma unroll
        for (int e = 1; e <= ND; ++e) {
            const float S_cur = tree[NC - (1 << (11 - e)) + (t >> e)];
            if (S_prev != 0.0f)
                loss += wrow[e - 1] * (-logf(S_prev / S_cur));
            S_prev = S_cur;
        }
        atomicAdd(out, loss * (1.0f / NB));
    }
}

extern "C" void kernel_launch(void* const* d_in, const int* in_sizes, int n_in,
                              void* d_out, int out_size, void* d_ws, size_t ws_size,
                              hipStream_t stream)
{
    const float* inputs  = (const float*)d_in[0];
    const int*   target  = (const int*)d_in[1];
    // d_in[2], d_in[3] (onehot_num/onehot_den) are algebraically eliminated.
    const float* weights = (const float*)d_in[4];
    float* out = (float*)d_out;

    hipMemsetAsync(out, 0, sizeof(float), stream);  // harness poisons d_out with 0xAA
    hice_kernel<<<NB, 256, 0, stream>>>(inputs, target, weights, out);
}

// Round 2
// 111.219 us; speedup vs baseline: 1.2137x; 1.2137x over previous
//
#include <hip/hip_runtime.h>

// HiCE hierarchical cross-entropy, wave-per-sample formulation.
// num[e]/den[e] = S_e / S_{e+1}: S_e = exp-sum of the 2^e-leaf ancestor block
// of the target (softmax denominator cancels). A 64-lane wave computes all
// 11 levels: lane-local sums give level 4, shfl_xor butterflies give 5..10,
// the target lane's registers give 0..3. No atomics, no syncthreads hot path.

#define NB 2048   // batch
#define NC 1024   // classes = 2^ND
#define ND 10     // edges
#define WPB 4     // waves (samples) per block
#define GRID1 (NB / WPB)   // 512 blocks

__global__ __launch_bounds__(256) void hice_stage1(
    const float* __restrict__ inputs,   // [NB, NC]
    const int*   __restrict__ target,   // [NB]
    const float* __restrict__ weights,  // [NC, ND]
    float*       __restrict__ partial)  // [GRID1]
{
    const int tid  = threadIdx.x;
    const int w    = tid >> 6;
    const int lane = tid & 63;
    const int b    = blockIdx.x * WPB + w;

    const float4* x4 = (const float4*)(inputs + (size_t)b * NC);

    // Each lane owns 16 contiguous leaves [lane*16, lane*16+16).
    float4 q0 = x4[lane * 4 + 0];
    float4 q1 = x4[lane * 4 + 1];
    float4 q2 = x4[lane * 4 + 2];
    float4 q3 = x4[lane * 4 + 3];
    float v[16] = {q0.x,q0.y,q0.z,q0.w, q1.x,q1.y,q1.z,q1.w,
                   q2.x,q2.y,q2.z,q2.w, q3.x,q3.y,q3.z,q3.w};

    // ---- wave max (numerical stability) ----
    float m = v[0];
#pragma unroll
    for (int i = 1; i < 16; ++i) m = fmaxf(m, v[i]);
#pragma unroll
    for (int off = 32; off > 0; off >>= 1)
        m = fmaxf(m, __shfl_xor(m, off, 64));

    // ---- exp in place; lane-local sum = level-4 node for this lane ----
    float s = 0.0f;
#pragma unroll
    for (int i = 0; i < 16; ++i) {
        v[i] = expf(v[i] - m);
        s += v[i];
    }

    const int t = target[b];        // wave-uniform
    const int j = t & 15;           // leaf position within owning lane

    // ---- levels 0..3 from registers (wave-uniform predicates, no divergence;
    //      only lane (t>>4)'s result is used) ----
    float S0 = 0.f, S1 = 0.f, S2 = 0.f, S3 = 0.f;
#pragma unroll
    for (int i = 0; i < 16; ++i) {
        S0 += (i == j)               ? v[i] : 0.f;
        S1 += ((i >> 1) == (j >> 1)) ? v[i] : 0.f;
        S2 += ((i >> 2) == (j >> 2)) ? v[i] : 0.f;
        S3 += ((i >> 3) == (j >> 3)) ? v[i] : 0.f;
    }

    // ---- levels 5..10 via butterfly: after step d each lane holds its
    //      level-(5+d) ancestor block sum ----
    float S[ND + 1];
    S[0] = S0; S[1] = S1; S[2] = S2; S[3] = S3; S[4] = s;
    float cur = s;
#pragma unroll
    for (int d = 0; d < 6; ++d) {
        cur += __shfl_xor(cur, 1 << d, 64);
        S[5 + d] = cur;
    }

    // ---- loss (every lane computes with its own path; lane t>>4 is correct) ----
    const float* wrow = weights + (size_t)t * ND;
    float loss = 0.0f;
#pragma unroll
    for (int e = 1; e <= ND; ++e) {
        const float Sp = S[e - 1], Sc = S[e];
        const bool nz = (Sp != 0.0f);
        const float r = (nz ? Sp : 1.0f) / (nz ? Sc : 1.0f);
        loss += nz ? wrow[e - 1] * (-logf(r)) : 0.0f;
    }
    loss = __shfl(loss, t >> 4, 64);   // broadcast the correct lane's loss

    // ---- 4 waves -> 1 partial per block ----
    __shared__ float wloss[WPB];
    if (lane == 0) wloss[w] = loss;
    __syncthreads();
    if (tid == 0)
        partial[blockIdx.x] = wloss[0] + wloss[1] + wloss[2] + wloss[3];
}

__global__ __launch_bounds__(256) void hice_stage2(
    const float* __restrict__ partial,  // [GRID1] = 512
    float*       __restrict__ out)      // [1]
{
    const int tid = threadIdx.x;
    float s = partial[tid] + partial[tid + 256];
#pragma unroll
    for (int off = 32; off > 0; off >>= 1)
        s += __shfl_xor(s, off, 64);
    __shared__ float ws[4];
    if ((tid & 63) == 0) ws[tid >> 6] = s;
    __syncthreads();
    if (tid == 0)
        out[0] = (ws[0] + ws[1] + ws[2] + ws[3]) * (1.0f / NB);
}

extern "C" void kernel_launch(void* const* d_in, const int* in_sizes, int n_in,
                              void* d_out, int out_size, void* d_ws, size_t ws_size,
                              hipStream_t stream)
{
    const float* inputs  = (const float*)d_in[0];
    const int*   target  = (const int*)d_in[1];
    // d_in[2], d_in[3] (onehot_num/onehot_den) are algebraically eliminated.
    const float* weights = (const float*)d_in[4];
    float* partial = (float*)d_ws;      // 512 floats of scratch
    float* out = (float*)d_out;

    hice_stage1<<<GRID1, 256, 0, stream>>>(inputs, target, weights, partial);
    hice_stage2<<<1, 256, 0, stream>>>(partial, out);
}